// Round 2
// baseline (823.710 us; speedup 1.0000x reference)
//
#include <hip/hip_runtime.h>

#define ENTITIES_N 100000
#define RELATIONS_N 1000
#define WIDTH (2 * ENTITIES_N + RELATIONS_N)   // 201000
#define BATCH_ROWS 1024                        // fixed by the problem (BATCH = 1024)
#define CHUNKS_PER_ROW (WIDTH / 4)             // 50250 float4 chunks, exact (201000 % 4 == 0)

// Structure (R2): ONE fused kernel replaces hipMemsetAsync + scatter.
// Evidence: the 3.29 GB / ~520 us fillBufferAligned seen in rocprof is the
// HARNESS's fill of its own 4x-sized allocation (invariant to our memset size),
// while our 823 MB memset ran at only ~3.3 TB/s (~250 us; prev session's
// measurement). The harness fill proves ~6.3 TB/s is achievable for pure
// stores, so we write the zeros ourselves with coalesced float4 stores and
// predicate the three 1.0f's inline (h/r/t column segments are disjoint).
// One block per row: h/r/t loads are block-uniform (hoisted, scalarizable);
// 256 threads stride the row's 50,250 float4 chunks -> 1 KB per wave-store.
template <typename IdxT>
__global__ __launch_bounds__(256) void fill_fused(
    const IdxT* __restrict__ hID, const int* __restrict__ rID,
    const int* __restrict__ tID, float* __restrict__ out) {
  const int row = blockIdx.x;
  const int h = (int)hID[row];                              // col of h-one
  const int r = ENTITIES_N + rID[row];                      // col of r-one
  const int t = ENTITIES_N + RELATIONS_N + tID[row];        // col of t-one
  float4* __restrict__ orow =
      reinterpret_cast<float4*>(out + (long long)row * WIDTH);  // 16B-aligned: row*804000 bytes
  for (int j = threadIdx.x; j < CHUNKS_PER_ROW; j += 256) {
    const int c0 = j * 4;  // first column covered by this chunk
    float4 v;
    // Static component-wise predication (no runtime vector indexing -> no scratch).
    v.x = (c0     == h || c0     == r || c0     == t) ? 1.0f : 0.0f;
    v.y = (c0 + 1 == h || c0 + 1 == r || c0 + 1 == t) ? 1.0f : 0.0f;
    v.z = (c0 + 2 == h || c0 + 2 == r || c0 + 2 == t) ? 1.0f : 0.0f;
    v.w = (c0 + 3 == h || c0 + 3 == r || c0 + 3 == t) ? 1.0f : 0.0f;
    orow[j] = v;
  }
}

extern "C" void kernel_launch(void* const* d_in, const int* in_sizes, int n_in,
                              void* d_out, int out_size, void* d_ws, size_t ws_size,
                              hipStream_t stream) {
  // Inputs (setup_inputs order): z [B,128] f32 (unused), hID [B] int32/int64,
  // rID [B] i32, tID [B] i32.
  const int* rID = (const int*)d_in[2];
  const int* tID = (const int*)d_in[3];
  float* out = (float*)d_out;

  // One block per row; each block streams 804 KB of zeros + its 3 ones.
  // hID dtype: jax x64 is off in this harness (both prior rounds passed on the
  // i32 path); the size-ratio test still routes i64 if sizes are in bytes.
  if (in_sizes[1] == 2 * in_sizes[3]) {
    fill_fused<long long><<<BATCH_ROWS, 256, 0, stream>>>(
        (const long long*)d_in[1], rID, tID, out);
  } else {
    fill_fused<int><<<BATCH_ROWS, 256, 0, stream>>>(
        (const int*)d_in[1], rID, tID, out);
  }
}

// Round 3
// 770.807 us; speedup vs baseline: 1.0686x; 1.0686x over previous
//
#include <hip/hip_runtime.h>

#define ENTITIES_N 100000
#define RELATIONS_N 1000
#define WIDTH (2 * ENTITIES_N + RELATIONS_N)   // 201000
#define BATCH_ROWS 1024                        // fixed by the problem (BATCH = 1024)

// Total output: 1024 * 201000 floats = 823,296,000 B = 51,456,000 float4s.
#define TOTAL_F4 (BATCH_ROWS * (WIDTH / 4))    // 51,456,000
#define FILL_BLOCK 256
#define FILL_GRID (TOTAL_F4 / FILL_BLOCK)      // 201,000 blocks, exact

// R3 structure: mimic the rocclr fillBufferAligned shape, which rocprof proves
// sustains 6.25 TB/s of pure HBM stores ON THIS BUFFER (it's a compute shader:
// wg=256, VGPR=8 — not SDMA). Key shape property: store-and-exit — each thread
// issues ONE float4 store and retires; no loops, no resident waves waiting.
// Our loop-based variants (R2 fused, prior session's nt/plain/ILP) all plateau
// at ~2.8 TB/s; the SDMA memset node does 3.3 TB/s. Target: ~130-160 us for
// the 823 MB zero instead of 250-300 us.
__global__ __launch_bounds__(FILL_BLOCK) void zero_fill(float4* __restrict__ out4) {
  const unsigned i = blockIdx.x * FILL_BLOCK + threadIdx.x;  // < 51.5M, fits u32
  out4[i] = make_float4(0.0f, 0.0f, 0.0f, 0.0f);
}

// Tiny scatter: 3*1024 ones. h/r/t column segments are disjoint -> no conflicts.
__global__ void scatter_ones_i32(const int* __restrict__ hID,
                                 const int* __restrict__ rID,
                                 const int* __restrict__ tID,
                                 float* __restrict__ out) {
  int row = blockIdx.x * blockDim.x + threadIdx.x;
  if (row >= BATCH_ROWS) return;
  long long base = (long long)row * WIDTH;
  out[base + (long long)hID[row]] = 1.0f;
  out[base + ENTITIES_N + (long long)rID[row]] = 1.0f;
  out[base + ENTITIES_N + RELATIONS_N + (long long)tID[row]] = 1.0f;
}

__global__ void scatter_ones_i64(const long long* __restrict__ hID,
                                 const int* __restrict__ rID,
                                 const int* __restrict__ tID,
                                 float* __restrict__ out) {
  int row = blockIdx.x * blockDim.x + threadIdx.x;
  if (row >= BATCH_ROWS) return;
  long long base = (long long)row * WIDTH;
  out[base + hID[row]] = 1.0f;
  out[base + ENTITIES_N + (long long)rID[row]] = 1.0f;
  out[base + ENTITIES_N + RELATIONS_N + (long long)tID[row]] = 1.0f;
}

extern "C" void kernel_launch(void* const* d_in, const int* in_sizes, int n_in,
                              void* d_out, int out_size, void* d_ws, size_t ws_size,
                              hipStream_t stream) {
  // Inputs (setup_inputs order): z [B,128] f32 (unused), hID [B] int32/int64,
  // rID [B] i32, tID [B] i32.
  const int* rID = (const int*)d_in[2];
  const int* tID = (const int*)d_in[3];
  float* out = (float*)d_out;

  // 823 MB of zeros at the fillBufferAligned shape (store-and-exit, huge grid).
  zero_fill<<<FILL_GRID, FILL_BLOCK, 0, stream>>>(reinterpret_cast<float4*>(out));

  // Then the 3*1024 ones (must order after the fill; same stream serializes).
  const int block = 256;
  const int grid = (BATCH_ROWS + block - 1) / block;  // 4 workgroups
  if (in_sizes[1] == 2 * in_sizes[3]) {
    scatter_ones_i64<<<grid, block, 0, stream>>>((const long long*)d_in[1], rID, tID, out);
  } else {
    scatter_ones_i32<<<grid, block, 0, stream>>>((const int*)d_in[1], rID, tID, out);
  }
}